// Round 5
// baseline (244.299 us; speedup 1.0000x reference)
//
#include <hip/hip_runtime.h>

#define BINS   10
#define CSHIFT 26
#define QMASK  0x03FFFFFFu
#define QSCALE 2097152.0f        // 2^21 quanta per loss unit
#define QLN2   1453635.25f       // ln2 * 2^21: q = round(log2(1+em) * QLN2)
#define GRID   1536              // 6 blocks/CU co-resident (24 KB LDS each)
#define TPB    256

// PRIMARY ws layout (private slots, no atomics, no zeroing needed):
//   u32  cnt[b][bid]  at word  b*GRID + bid          (b = 0..9, cumulative)
//   f32  q  [b][bid]  at word (BINS+b)*GRID + bid    (pre-scaled by 1/QSCALE)
// FALLBACK (ws too small): padded-atomic layout + zero kernel.

__global__ void ghm_zero_ws(unsigned* ws) {
    if (threadIdx.x < 320) ws[threadIdx.x] = 0u;   // 10 x 128 B padded slots
}

// Async global->LDS DMA, 16 B/lane. LDS dest = wave-uniform base + lane*16.
__device__ __forceinline__ void gld_lds16(const void* g, void* l) {
    __builtin_amdgcn_global_load_lds(
        (const __attribute__((address_space(1))) void*)g,
        (__attribute__((address_space(3))) void*)l, 16, 0, 0);
}

// bin b <=> D[b+1] < d <= D[b], D[b] = ln(20/b - 1); cumulative A[b] over d>Th[b].
// Packed u32: count in [31:26], quantized loss sum in [25:0].
// Per-thread bounds (<=44 samples/thread at GRID=1536):
//   count<=44<64; q<=44*1.45M=64M<2^26. OK.
__device__ __forceinline__ void proc1(float o0, float o1, int t, unsigned* A) {
    const float Th[BINS] = {
        2.9444390f, 2.1972246f, 1.7346011f, 1.3862944f, 1.0986123f,
        0.8472979f, 0.6190392f, 0.4054651f, 0.2006707f, 0.0f };
    float s = o0 - o1;
    float d = __int_as_float(__float_as_int(s) ^ (t << 31));  // target - other
    float em = __expf(-d);
    float qf = fmaf(__log2f(1.0f + em), QLN2, 0.5f);  // round(loss * 2^21)
    unsigned val = (unsigned)qf + (1u << CSHIFT);     // d<=0 lanes: masked below
    #pragma unroll
    for (int b = 0; b < BINS; ++b)
        A[b] += (d > Th[b]) ? val : 0u;
}

// Barrier-free per-wave DMA ring. Each wave owns 256-sample tiles: it stages
// (2 KB outs + 1 KB tgt = 3 gld_lds16) into its PRIVATE LDS slot and consumes
// only what it staged -> no cross-wave dependency -> no __syncthreads, no
// vmcnt(0) drain in the hot loop. Counted s_waitcnt vmcnt(3) keeps the other
// slot's 3 loads permanently in flight (T4: never drain to 0 mid-loop).
__global__ __launch_bounds__(TPB, 6)
void ghm_main(const float* __restrict__ outs,   // [n,2] f32
              const int*   __restrict__ tgt,    // [n]   i32
              unsigned char* __restrict__ ws,
              int n, int use_slots) {
    __shared__ __align__(16) union {
        unsigned char ring[4][2][3072];        // [wave][slot][2KB outs|1KB tgt]
        struct {
            unsigned h[BINS][256];             // 10 KB epilogue scratch
            unsigned c[BINS][16];
            float    q[BINS][16];
        } ep;
    } sh;                                      // 24 KB -> 6 blocks/CU

    const int tid  = threadIdx.x;
    const int lane = tid & 63;
    const int wv   = tid >> 6;

    unsigned A[BINS];
    #pragma unroll
    for (int b = 0; b < BINS; ++b) A[b] = 0u;

    const int NT = n >> 8;                     // full 256-sample wave-tiles
    const int NW = gridDim.x << 2;             // total waves = 6144
    const int gw = (blockIdx.x << 2) + wv;     // this wave's id

    const char* outs_b = (const char*)outs;
    const char* tgt_b  = (const char*)tgt;
    unsigned char* r0 = sh.ring[wv][0];
    unsigned char* r1 = sh.ring[wv][1];

    // 3 issues per tile; vmcnt FIFO is per-wave (m135: in-order retirement).
    #define STAGE(tile, rp)                                                     \
        do {                                                                    \
            const char* go = outs_b + ((size_t)(tile) << 11) + (lane << 4);     \
            gld_lds16(go,        (char*)(rp));                                  \
            gld_lds16(go + 1024, (char*)(rp) + 1024);                           \
            gld_lds16(tgt_b + ((size_t)(tile) << 10) + (lane << 4),             \
                      (char*)(rp) + 2048);                                      \
        } while (0)

    int t = gw;
    if (t < NT) {
        STAGE(t, r0);                          // prologue: 3 outstanding
        int cur = 0;
        for (; t < NT; t += NW) {
            int tn = t + NW;
            if (tn >= NT) tn = 0;              // clamp: uniform 3-issue count
            STAGE(tn, cur ? r0 : r1);          // outstanding -> 6
            // Oldest 3 (current slot) done; next slot's 3 stay in flight.
            asm volatile("s_waitcnt vmcnt(3)" ::: "memory");
            __builtin_amdgcn_sched_barrier(0);
            const unsigned char* rp = cur ? r1 : r0;
            const float4* o4 = (const float4*)rp;
            const int4*   t4 = (const int4*)(rp + 2048);
            float4 a  = o4[2 * lane];
            float4 bq = o4[2 * lane + 1];
            int4   tv = t4[lane];
            proc1(a.x,  a.y,  tv.x, A);
            proc1(a.z,  a.w,  tv.y, A);
            proc1(bq.x, bq.y, tv.z, A);
            proc1(bq.z, bq.w, tv.w, A);
            cur ^= 1;
        }
    }

    // tail samples (n % 256; zero at N=2^24) — block 0, direct from global
    int rem = NT << 8;
    if (blockIdx.x == 0) {
        for (int s = rem + tid; s < n; s += TPB)
            proc1(outs[2 * s], outs[2 * s + 1], tgt[s], A);
    }

    // ---- epilogue ----
    // __syncthreads drains vmcnt(0): straggler/clamped DMAs land in the ring
    // BEFORE any wave re-purposes the union as ep scratch.
    __syncthreads();
    #pragma unroll
    for (int b = 0; b < BINS; ++b) sh.ep.h[b][tid] = A[b];
    __syncthreads();

    if (tid < 16 * BINS) {
        int bin  = tid >> 4;
        int part = tid & 15;
        unsigned c = 0, q = 0;                 // q <= 16*64M ~ 1.0e9 < 2^32
        #pragma unroll
        for (int j = 0; j < 16; ++j) {
            unsigned v = sh.ep.h[bin][j * 16 + part];
            c += v >> CSHIFT;
            q += v & QMASK;
        }
        sh.ep.c[bin][part] = c;
        sh.ep.q[bin][part] = (float)q;
    }
    __syncthreads();
    if (tid < BINS) {
        unsigned c = 0; float q = 0.0f;
        #pragma unroll
        for (int j = 0; j < 16; ++j) { c += sh.ep.c[tid][j]; q += sh.ep.q[tid][j]; }
        if (use_slots) {                       // private slot: zero contention
            ((unsigned*)ws)[tid * GRID + blockIdx.x]        = c;
            ((float*)ws)[(BINS + tid) * GRID + blockIdx.x]  = q * (1.0f / QSCALE);
        } else if (c) {                        // fallback: padded atomics
            atomicAdd((unsigned*)(ws + 128 * tid + 64), c);
            atomicAdd((float*)   (ws + 128 * tid),      q * (1.0f / QSCALE));
        }
    }
}

// Reduce [20][GRID] private slots (123 KB, coalesced) -> scalar output.
__global__ __launch_bounds__(256)
void ghm_final2(const unsigned char* __restrict__ ws,
                const float* __restrict__ acc_sum,
                float* __restrict__ out) {
    __shared__ unsigned lc[BINS][256];
    __shared__ float    lq[BINS][256];
    __shared__ unsigned sc[BINS][16];
    __shared__ float    sq[BINS][16];
    const int tid = threadIdx.x;
    const unsigned* cb = (const unsigned*)ws;
    const float*    qb = (const float*)ws + (size_t)BINS * GRID;

    unsigned c[BINS]; float q[BINS];
    #pragma unroll
    for (int b = 0; b < BINS; ++b) { c[b] = 0u; q[b] = 0.0f; }
    for (int r = tid; r < GRID; r += 256) {
        #pragma unroll
        for (int b = 0; b < BINS; ++b) {
            c[b] += cb[b * GRID + r];
            q[b] += qb[b * GRID + r];
        }
    }
    #pragma unroll
    for (int b = 0; b < BINS; ++b) { lc[b][tid] = c[b]; lq[b][tid] = q[b]; }
    __syncthreads();

    if (tid < 16 * BINS) {
        int bin = tid >> 4, part = tid & 15;
        unsigned cc = 0u; float cq = 0.0f;
        #pragma unroll
        for (int j = 0; j < 16; ++j) {
            cc += lc[bin][j * 16 + part];
            cq += lq[bin][j * 16 + part];
        }
        sc[bin][part] = cc;
        sq[bin][part] = cq;
    }
    __syncthreads();

    if (tid == 0) {
        float r = 0.0f, pq = 0.0f;
        unsigned pc = 0u;
        #pragma unroll
        for (int b = 0; b < BINS; ++b) {       // cumulative -> per-bin diff
            unsigned cc = 0u; float cq = 0.0f;
            #pragma unroll
            for (int j = 0; j < 16; ++j) { cc += sc[b][j]; cq += sq[b][j]; }
            unsigned cnt = cc - pc;
            float    qs  = cq - pq;
            pc = cc; pq = cq;
            if (cnt > 0u) {
                float na = 0.75f * acc_sum[b] + 0.25f * (float)cnt;
                r += qs / na;    // = (1/N) * sum(loss_i * N/na[bin_i])
            }
        }
        *out = r;
    }
}

// Fallback finalization (padded-atomic layout).
__global__ void ghm_final(const unsigned char* __restrict__ ws,
                          const float* __restrict__ acc_sum,
                          float* __restrict__ out) {
    if (threadIdx.x == 0) {
        float r = 0.0f, pq = 0.0f;
        unsigned pc = 0u;
        #pragma unroll
        for (int b = 0; b < BINS; ++b) {
            float    cq = *(const float*)   (ws + 128 * b);
            unsigned cc = *(const unsigned*)(ws + 128 * b + 64);
            unsigned cnt = cc - pc;
            float    qs  = cq - pq;
            pc = cc; pq = cq;
            if (cnt > 0u) {
                float na = 0.75f * acc_sum[b] + 0.25f * (float)cnt;
                r += qs / na;
            }
        }
        *out = r;
    }
}

extern "C" void kernel_launch(void* const* d_in, const int* in_sizes, int n_in,
                              void* d_out, int out_size, void* d_ws, size_t ws_size,
                              hipStream_t stream) {
    const float* outputs = (const float*)d_in[0];  // [N,2] f32
    const int*   targets = (const int*)d_in[1];    // [N] int32
    const float* acc_sum = (const float*)d_in[2];  // [10] f32
    int n = in_sizes[1];

    const int use_slots = (ws_size >= (size_t)2 * BINS * GRID * 4) ? 1 : 0;

    if (!use_slots)
        ghm_zero_ws<<<1, 512, 0, stream>>>((unsigned*)d_ws);
    ghm_main<<<GRID, TPB, 0, stream>>>(outputs, targets,
                                       (unsigned char*)d_ws, n, use_slots);
    if (use_slots)
        ghm_final2<<<1, 256, 0, stream>>>((const unsigned char*)d_ws, acc_sum,
                                          (float*)d_out);
    else
        ghm_final<<<1, 64, 0, stream>>>((const unsigned char*)d_ws, acc_sum,
                                        (float*)d_out);
}

// Round 6
// 227.279 us; speedup vs baseline: 1.0749x; 1.0749x over previous
//
#include <hip/hip_runtime.h>

#define BINS   10
#define CSHIFT 26
#define QMASK  0x03FFFFFFu
#define QSCALE 2097152.0f        // 2^21 quanta per loss unit
#define QLN2   1453635.25f       // ln2 * 2^21: q = round(log2(1+em) * QLN2)
#define GRID   1536              // 6 blocks/CU co-resident (24 KB LDS each)
#define TPB    256

// PRIMARY ws layout (private slots, no atomics, no zeroing needed):
//   u32  cnt[b][bid]  at word  b*GRID + bid          (b = 0..9, cumulative)
//   f32  q  [b][bid]  at word (BINS+b)*GRID + bid    (pre-scaled by 1/QSCALE)
// FALLBACK (ws too small): padded-atomic layout + zero kernel.

__global__ void ghm_zero_ws(unsigned* ws) {
    if (threadIdx.x < 320) ws[threadIdx.x] = 0u;   // 10 x 128 B padded slots
}

// Async global->LDS DMA, 16 B/lane. LDS dest = wave-uniform base + lane*16.
// aux=2 sets the NT (non-temporal) CPol bit (gfx940+ encoding: sc0=1,nt=2,
// sc1=16): hint L2/L3 not to retain this once-read stream. Read-only data ->
// hints cannot affect correctness, only allocation/eviction behavior.
__device__ __forceinline__ void gld_lds16_nt(const void* g, void* l) {
    __builtin_amdgcn_global_load_lds(
        (const __attribute__((address_space(1))) void*)g,
        (__attribute__((address_space(3))) void*)l, 16, 0, 2);
}

// bin b <=> D[b+1] < d <= D[b], D[b] = ln(20/b - 1); cumulative A[b] over d>Th[b].
// Packed u32: count in [31:26], quantized loss sum in [25:0].
// Per-thread bounds (<=44 samples/thread at GRID=1536):
//   count<=44<64; q<=44*1.45M=64M<2^26. OK.
__device__ __forceinline__ void proc1(float o0, float o1, int t, unsigned* A) {
    const float Th[BINS] = {
        2.9444390f, 2.1972246f, 1.7346011f, 1.3862944f, 1.0986123f,
        0.8472979f, 0.6190392f, 0.4054651f, 0.2006707f, 0.0f };
    float s = o0 - o1;
    float d = __int_as_float(__float_as_int(s) ^ (t << 31));  // target - other
    float em = __expf(-d);
    float qf = fmaf(__log2f(1.0f + em), QLN2, 0.5f);  // round(loss * 2^21)
    unsigned val = (unsigned)qf + (1u << CSHIFT);     // d<=0 lanes: masked below
    #pragma unroll
    for (int b = 0; b < BINS; ++b)
        A[b] += (d > Th[b]) ? val : 0u;
}

// Barrier-free per-wave DMA ring (R5 structure, single change: NT cache hint).
// Each wave owns 256-sample tiles staged into its PRIVATE LDS slot; counted
// s_waitcnt vmcnt(3) keeps the next slot's 3 loads permanently in flight.
__global__ __launch_bounds__(TPB, 6)
void ghm_main(const float* __restrict__ outs,   // [n,2] f32
              const int*   __restrict__ tgt,    // [n]   i32
              unsigned char* __restrict__ ws,
              int n, int use_slots) {
    __shared__ __align__(16) union {
        unsigned char ring[4][2][3072];        // [wave][slot][2KB outs|1KB tgt]
        struct {
            unsigned h[BINS][256];             // 10 KB epilogue scratch
            unsigned c[BINS][16];
            float    q[BINS][16];
        } ep;
    } sh;                                      // 24 KB -> 6 blocks/CU

    const int tid  = threadIdx.x;
    const int lane = tid & 63;
    const int wv   = tid >> 6;

    unsigned A[BINS];
    #pragma unroll
    for (int b = 0; b < BINS; ++b) A[b] = 0u;

    const int NT = n >> 8;                     // full 256-sample wave-tiles
    const int NW = gridDim.x << 2;             // total waves = 6144
    const int gw = (blockIdx.x << 2) + wv;     // this wave's id

    const char* outs_b = (const char*)outs;
    const char* tgt_b  = (const char*)tgt;
    unsigned char* r0 = sh.ring[wv][0];
    unsigned char* r1 = sh.ring[wv][1];

    // 3 issues per tile; vmcnt FIFO is per-wave (m135: in-order retirement).
    #define STAGE(tile, rp)                                                     \
        do {                                                                    \
            const char* go = outs_b + ((size_t)(tile) << 11) + (lane << 4);     \
            gld_lds16_nt(go,        (char*)(rp));                               \
            gld_lds16_nt(go + 1024, (char*)(rp) + 1024);                        \
            gld_lds16_nt(tgt_b + ((size_t)(tile) << 10) + (lane << 4),          \
                         (char*)(rp) + 2048);                                   \
        } while (0)

    int t = gw;
    if (t < NT) {
        STAGE(t, r0);                          // prologue: 3 outstanding
        int cur = 0;
        for (; t < NT; t += NW) {
            int tn = t + NW;
            if (tn >= NT) tn = 0;              // clamp: uniform 3-issue count
            STAGE(tn, cur ? r0 : r1);          // outstanding -> 6
            // Oldest 3 (current slot) done; next slot's 3 stay in flight.
            asm volatile("s_waitcnt vmcnt(3)" ::: "memory");
            __builtin_amdgcn_sched_barrier(0);
            const unsigned char* rp = cur ? r1 : r0;
            const float4* o4 = (const float4*)rp;
            const int4*   t4 = (const int4*)(rp + 2048);
            float4 a  = o4[2 * lane];
            float4 bq = o4[2 * lane + 1];
            int4   tv = t4[lane];
            proc1(a.x,  a.y,  tv.x, A);
            proc1(a.z,  a.w,  tv.y, A);
            proc1(bq.x, bq.y, tv.z, A);
            proc1(bq.z, bq.w, tv.w, A);
            cur ^= 1;
        }
    }

    // tail samples (n % 256; zero at N=2^24) — block 0, direct from global
    int rem = NT << 8;
    if (blockIdx.x == 0) {
        for (int s = rem + tid; s < n; s += TPB)
            proc1(outs[2 * s], outs[2 * s + 1], tgt[s], A);
    }

    // ---- epilogue ----
    // __syncthreads drains vmcnt(0): straggler/clamped DMAs land in the ring
    // BEFORE any wave re-purposes the union as ep scratch.
    __syncthreads();
    #pragma unroll
    for (int b = 0; b < BINS; ++b) sh.ep.h[b][tid] = A[b];
    __syncthreads();

    if (tid < 16 * BINS) {
        int bin  = tid >> 4;
        int part = tid & 15;
        unsigned c = 0, q = 0;                 // q <= 16*64M ~ 1.0e9 < 2^32
        #pragma unroll
        for (int j = 0; j < 16; ++j) {
            unsigned v = sh.ep.h[bin][j * 16 + part];
            c += v >> CSHIFT;
            q += v & QMASK;
        }
        sh.ep.c[bin][part] = c;
        sh.ep.q[bin][part] = (float)q;
    }
    __syncthreads();
    if (tid < BINS) {
        unsigned c = 0; float q = 0.0f;
        #pragma unroll
        for (int j = 0; j < 16; ++j) { c += sh.ep.c[tid][j]; q += sh.ep.q[tid][j]; }
        if (use_slots) {                       // private slot: zero contention
            ((unsigned*)ws)[tid * GRID + blockIdx.x]        = c;
            ((float*)ws)[(BINS + tid) * GRID + blockIdx.x]  = q * (1.0f / QSCALE);
        } else if (c) {                        // fallback: padded atomics
            atomicAdd((unsigned*)(ws + 128 * tid + 64), c);
            atomicAdd((float*)   (ws + 128 * tid),      q * (1.0f / QSCALE));
        }
    }
}

// Reduce [20][GRID] private slots (123 KB, coalesced) -> scalar output.
__global__ __launch_bounds__(256)
void ghm_final2(const unsigned char* __restrict__ ws,
                const float* __restrict__ acc_sum,
                float* __restrict__ out) {
    __shared__ unsigned lc[BINS][256];
    __shared__ float    lq[BINS][256];
    __shared__ unsigned sc[BINS][16];
    __shared__ float    sq[BINS][16];
    const int tid = threadIdx.x;
    const unsigned* cb = (const unsigned*)ws;
    const float*    qb = (const float*)ws + (size_t)BINS * GRID;

    unsigned c[BINS]; float q[BINS];
    #pragma unroll
    for (int b = 0; b < BINS; ++b) { c[b] = 0u; q[b] = 0.0f; }
    for (int r = tid; r < GRID; r += 256) {
        #pragma unroll
        for (int b = 0; b < BINS; ++b) {
            c[b] += cb[b * GRID + r];
            q[b] += qb[b * GRID + r];
        }
    }
    #pragma unroll
    for (int b = 0; b < BINS; ++b) { lc[b][tid] = c[b]; lq[b][tid] = q[b]; }
    __syncthreads();

    if (tid < 16 * BINS) {
        int bin = tid >> 4, part = tid & 15;
        unsigned cc = 0u; float cq = 0.0f;
        #pragma unroll
        for (int j = 0; j < 16; ++j) {
            cc += lc[bin][j * 16 + part];
            cq += lq[bin][j * 16 + part];
        }
        sc[bin][part] = cc;
        sq[bin][part] = cq;
    }
    __syncthreads();

    if (tid == 0) {
        float r = 0.0f, pq = 0.0f;
        unsigned pc = 0u;
        #pragma unroll
        for (int b = 0; b < BINS; ++b) {       // cumulative -> per-bin diff
            unsigned cc = 0u; float cq = 0.0f;
            #pragma unroll
            for (int j = 0; j < 16; ++j) { cc += sc[b][j]; cq += sq[b][j]; }
            unsigned cnt = cc - pc;
            float    qs  = cq - pq;
            pc = cc; pq = cq;
            if (cnt > 0u) {
                float na = 0.75f * acc_sum[b] + 0.25f * (float)cnt;
                r += qs / na;    // = (1/N) * sum(loss_i * N/na[bin_i])
            }
        }
        *out = r;
    }
}

// Fallback finalization (padded-atomic layout).
__global__ void ghm_final(const unsigned char* __restrict__ ws,
                          const float* __restrict__ acc_sum,
                          float* __restrict__ out) {
    if (threadIdx.x == 0) {
        float r = 0.0f, pq = 0.0f;
        unsigned pc = 0u;
        #pragma unroll
        for (int b = 0; b < BINS; ++b) {
            float    cq = *(const float*)   (ws + 128 * b);
            unsigned cc = *(const unsigned*)(ws + 128 * b + 64);
            unsigned cnt = cc - pc;
            float    qs  = cq - pq;
            pc = cc; pq = cq;
            if (cnt > 0u) {
                float na = 0.75f * acc_sum[b] + 0.25f * (float)cnt;
                r += qs / na;
            }
        }
        *out = r;
    }
}

extern "C" void kernel_launch(void* const* d_in, const int* in_sizes, int n_in,
                              void* d_out, int out_size, void* d_ws, size_t ws_size,
                              hipStream_t stream) {
    const float* outputs = (const float*)d_in[0];  // [N,2] f32
    const int*   targets = (const int*)d_in[1];    // [N] int32
    const float* acc_sum = (const float*)d_in[2];  // [10] f32
    int n = in_sizes[1];

    const int use_slots = (ws_size >= (size_t)2 * BINS * GRID * 4) ? 1 : 0;

    if (!use_slots)
        ghm_zero_ws<<<1, 512, 0, stream>>>((unsigned*)d_ws);
    ghm_main<<<GRID, TPB, 0, stream>>>(outputs, targets,
                                       (unsigned char*)d_ws, n, use_slots);
    if (use_slots)
        ghm_final2<<<1, 256, 0, stream>>>((const unsigned char*)d_ws, acc_sum,
                                          (float*)d_out);
    else
        ghm_final<<<1, 64, 0, stream>>>((const unsigned char*)d_ws, acc_sum,
                                        (float*)d_out);
}

// Round 7
// 225.506 us; speedup vs baseline: 1.0833x; 1.0079x over previous
//
#include <hip/hip_runtime.h>

#define BINS   10
#define CSHIFT 26
#define QMASK  0x03FFFFFFu
#define QSCALE 2097152.0f        // 2^21 quanta per loss unit
#define QLN2   1453635.25f       // ln2 * 2^21: q = round(log2(1+em) * QLN2)
#define GRID   2048              // 8 blocks/CU x 256 CU: exactly resident
#define TPB    256

// PRIMARY ws layout (private slots, no atomics, no zeroing needed):
//   u32  cnt[b][bid]  at word  b*GRID + bid          (b = 0..9, cumulative)
//   f32  q  [b][bid]  at word (BINS+b)*GRID + bid    (pre-scaled by 1/QSCALE)
//   total 20*GRID*4 = 163840 B; every word overwritten each launch.
// FALLBACK (ws too small): padded-atomic layout + zero kernel.

__global__ void ghm_zero_ws(unsigned* ws) {
    if (threadIdx.x < 320) ws[threadIdx.x] = 0u;   // 10 x 128 B padded slots
}

// Non-temporal 16 B vector load: global_load_dwordx4 with the NT cache-policy
// bit. R6 showed NT staging loads cut main ~17 us (the harness's 512 MiB ws
// poison-fill dirties L2/L3 every replay; NT reads skip allocate/evict-dirty).
typedef unsigned uv4 __attribute__((ext_vector_type(4)));
__device__ __forceinline__ uv4 nt16(const void* p) {
    return __builtin_nontemporal_load((const uv4*)p);
}
__device__ __forceinline__ float uf(unsigned u) { return __uint_as_float(u); }

// bin b <=> D[b+1] < d <= D[b], D[b] = ln(20/b - 1); cumulative A[b] over d>Th[b].
// Packed u32: count in [31:26], quantized loss sum in [25:0].
// Per-thread bounds (n=2^24, GRID*TPB=2^19 -> 32 samples/thread):
//   count<=32<64; q<=32*1.45M=46.5M<2^26=67.1M. OK.
__device__ __forceinline__ void proc1(float o0, float o1, int t, unsigned* A) {
    const float Th[BINS] = {
        2.9444390f, 2.1972246f, 1.7346011f, 1.3862944f, 1.0986123f,
        0.8472979f, 0.6190392f, 0.4054651f, 0.2006707f, 0.0f };
    float s = o0 - o1;
    float d = __int_as_float(__float_as_int(s) ^ (t << 31));  // target - other
    float em = __expf(-d);
    float qf = fmaf(__log2f(1.0f + em), QLN2, 0.5f);  // round(loss * 2^21)
    unsigned val = (unsigned)qf + (1u << CSHIFT);     // d<=0 lanes: masked below
    #pragma unroll
    for (int b = 0; b < BINS; ++b)
        A[b] += (d > Th[b]) ? val : 0u;
}

// Direct NT register streaming at max occupancy (8 waves/SIMD). Tests whether
// the NT win generalizes off the LDS-DMA path and stacks with 32 waves/CU.
__global__ __launch_bounds__(TPB, 8)
void ghm_main(const float* __restrict__ outs,   // [n,2] f32
              const int*   __restrict__ tgt,    // [n]   i32
              unsigned char* __restrict__ ws,
              int n, int use_slots) {
    __shared__ unsigned h[BINS][TPB];            // 10 KB epilogue scratch
    __shared__ unsigned sc[BINS][16];
    __shared__ float    sq[BINS][16];

    const int tid = threadIdx.x;

    unsigned A[BINS];
    #pragma unroll
    for (int b = 0; b < BINS; ++b) A[b] = 0u;

    // Register double-buffer: issue iter i+1's 3 NT dwordx4 loads before
    // computing iter i (keeps ~3 KB/wave in flight through the compute phase).
    const int nq = n >> 2;                 // sample-quads; 2^22 at N=2^24
    const int stride = gridDim.x * TPB;
    const uv4* __restrict__ o4 = (const uv4*)outs;   // 2 per quad
    const uv4* __restrict__ t4 = (const uv4*)tgt;    // 1 per quad

    int i = blockIdx.x * TPB + tid;
    bool have = i < nq;
    uv4 a0 = {}, b0 = {}, t0 = {};
    uv4 a1 = {}, b1 = {}, t1 = {};
    if (have) {
        a0 = nt16(o4 + 2 * (size_t)i);
        b0 = nt16(o4 + 2 * (size_t)i + 1);
        t0 = nt16(t4 + i);
    }
    while (have) {
        const int  i1    = i + stride;
        const bool have1 = i1 < nq;
        if (have1) {                       // next-iter loads issue FIRST
            a1 = nt16(o4 + 2 * (size_t)i1);
            b1 = nt16(o4 + 2 * (size_t)i1 + 1);
            t1 = nt16(t4 + i1);
        }
        proc1(uf(a0.x), uf(a0.y), (int)t0.x, A);
        proc1(uf(a0.z), uf(a0.w), (int)t0.y, A);
        proc1(uf(b0.x), uf(b0.y), (int)t0.z, A);
        proc1(uf(b0.z), uf(b0.w), (int)t0.w, A);
        a0 = a1; b0 = b1; t0 = t1;
        i = i1; have = have1;
    }

    // tail samples (n % 4; zero at N=2^24) — block 0, direct from global
    if (blockIdx.x == 0) {
        for (int s = (nq << 2) + tid; s < n; s += TPB)
            proc1(outs[2 * s], outs[2 * s + 1], tgt[s], A);
    }

    // ---- epilogue: dump packed regs, tree-reduce, 20 plain stores/block ----
    #pragma unroll
    for (int b = 0; b < BINS; ++b) h[b][tid] = A[b];
    __syncthreads();

    if (tid < 16 * BINS) {
        int bin  = tid >> 4;
        int part = tid & 15;
        unsigned c = 0, q = 0;              // q <= 16*46.5M ~ 7.4e8 < 2^32
        #pragma unroll
        for (int j = 0; j < 16; ++j) {
            unsigned v = h[bin][j * 16 + part];
            c += v >> CSHIFT;
            q += v & QMASK;
        }
        sc[bin][part] = c;
        sq[bin][part] = (float)q;
    }
    __syncthreads();
    if (tid < BINS) {
        unsigned c = 0; float q = 0.0f;
        #pragma unroll
        for (int j = 0; j < 16; ++j) { c += sc[tid][j]; q += sq[tid][j]; }
        if (use_slots) {                       // private slot: zero contention
            ((unsigned*)ws)[tid * GRID + blockIdx.x]        = c;
            ((float*)ws)[(BINS + tid) * GRID + blockIdx.x]  = q * (1.0f / QSCALE);
        } else if (c) {                        // fallback: padded atomics
            atomicAdd((unsigned*)(ws + 128 * tid + 64), c);
            atomicAdd((float*)   (ws + 128 * tid),      q * (1.0f / QSCALE));
        }
    }
}

// Reduce [20][GRID] private slots (160 KB, coalesced) -> scalar output.
__global__ __launch_bounds__(256)
void ghm_final2(const unsigned char* __restrict__ ws,
                const float* __restrict__ acc_sum,
                float* __restrict__ out) {
    __shared__ unsigned lc[BINS][256];
    __shared__ float    lq[BINS][256];
    __shared__ unsigned sc[BINS][16];
    __shared__ float    sq[BINS][16];
    const int tid = threadIdx.x;
    const unsigned* cb = (const unsigned*)ws;
    const float*    qb = (const float*)ws + (size_t)BINS * GRID;

    unsigned c[BINS]; float q[BINS];
    #pragma unroll
    for (int b = 0; b < BINS; ++b) { c[b] = 0u; q[b] = 0.0f; }
    for (int r = tid; r < GRID; r += 256) {    // 8 coalesced rounds x 20 loads
        #pragma unroll
        for (int b = 0; b < BINS; ++b) {
            c[b] += cb[b * GRID + r];
            q[b] += qb[b * GRID + r];
        }
    }
    #pragma unroll
    for (int b = 0; b < BINS; ++b) { lc[b][tid] = c[b]; lq[b][tid] = q[b]; }
    __syncthreads();

    if (tid < 16 * BINS) {
        int bin = tid >> 4, part = tid & 15;
        unsigned cc = 0u; float cq = 0.0f;
        #pragma unroll
        for (int j = 0; j < 16; ++j) {
            cc += lc[bin][j * 16 + part];
            cq += lq[bin][j * 16 + part];
        }
        sc[bin][part] = cc;
        sq[bin][part] = cq;
    }
    __syncthreads();

    if (tid == 0) {
        float r = 0.0f, pq = 0.0f;
        unsigned pc = 0u;
        #pragma unroll
        for (int b = 0; b < BINS; ++b) {       // cumulative -> per-bin diff
            unsigned cc = 0u; float cq = 0.0f;
            #pragma unroll
            for (int j = 0; j < 16; ++j) { cc += sc[b][j]; cq += sq[b][j]; }
            unsigned cnt = cc - pc;
            float    qs  = cq - pq;
            pc = cc; pq = cq;
            if (cnt > 0u) {
                float na = 0.75f * acc_sum[b] + 0.25f * (float)cnt;
                r += qs / na;    // = (1/N) * sum(loss_i * N/na[bin_i])
            }
        }
        *out = r;
    }
}

// Fallback finalization (padded-atomic layout).
__global__ void ghm_final(const unsigned char* __restrict__ ws,
                          const float* __restrict__ acc_sum,
                          float* __restrict__ out) {
    if (threadIdx.x == 0) {
        float r = 0.0f, pq = 0.0f;
        unsigned pc = 0u;
        #pragma unroll
        for (int b = 0; b < BINS; ++b) {
            float    cq = *(const float*)   (ws + 128 * b);
            unsigned cc = *(const unsigned*)(ws + 128 * b + 64);
            unsigned cnt = cc - pc;
            float    qs  = cq - pq;
            pc = cc; pq = cq;
            if (cnt > 0u) {
                float na = 0.75f * acc_sum[b] + 0.25f * (float)cnt;
                r += qs / na;
            }
        }
        *out = r;
    }
}

extern "C" void kernel_launch(void* const* d_in, const int* in_sizes, int n_in,
                              void* d_out, int out_size, void* d_ws, size_t ws_size,
                              hipStream_t stream) {
    const float* outputs = (const float*)d_in[0];  // [N,2] f32
    const int*   targets = (const int*)d_in[1];    // [N] int32
    const float* acc_sum = (const float*)d_in[2];  // [10] f32
    int n = in_sizes[1];

    const int use_slots = (ws_size >= (size_t)2 * BINS * GRID * 4) ? 1 : 0;

    if (!use_slots)
        ghm_zero_ws<<<1, 512, 0, stream>>>((unsigned*)d_ws);
    ghm_main<<<GRID, TPB, 0, stream>>>(outputs, targets,
                                       (unsigned char*)d_ws, n, use_slots);
    if (use_slots)
        ghm_final2<<<1, 256, 0, stream>>>((const unsigned char*)d_ws, acc_sum,
                                          (float*)d_out);
    else
        ghm_final<<<1, 64, 0, stream>>>((const unsigned char*)d_ws, acc_sum,
                                        (float*)d_out);
}